// Round 1
// baseline (580.781 us; speedup 1.0000x reference)
//
#include <hip/hip_runtime.h>

#define NTOK   65536
#define DIM    256
#define NCODE  1024
#define TT     128   // tokens per block
#define KTILE  128   // code tile
#define DTILE  32    // d tile

__global__ __launch_bounds__(256) void vq_kernel(
    const float* __restrict__ x, const float* __restrict__ W,
    float* __restrict__ outq, float* __restrict__ outidx)
{
    __shared__ float xs[DTILE][TT];        // 16 KB, [d][token]
    __shared__ float ws[DTILE][KTILE];     // 16 KB, [d][code]
    __shared__ float nw_s[NCODE];          // 4 KB
    __shared__ float nx_s[TT];             // 512 B
    __shared__ float red_d[16][TT + 1];    // padded: avoid 16-way bank conflict
    __shared__ int   red_k[16][TT + 1];
    __shared__ int   bk_s[TT];

    const int tid = threadIdx.x;
    const int tb  = blockIdx.x * TT;

    // ---- phase 0: ||W_k||^2 for all codes (fp64 acc -> fp32, mirrors ref sum
    //      accuracy), and ||x_t||^2 for this block's tokens ----
    #pragma unroll
    for (int c = 0; c < 4; ++c) {
        const int k = (tid << 2) + c;
        const float4* wr = (const float4*)(W + (size_t)k * DIM);
        double a0 = 0.0, a1 = 0.0;
        for (int q = 0; q < DIM / 4; ++q) {
            float4 v = wr[q];
            a0 += (double)v.x * v.x + (double)v.y * v.y;
            a1 += (double)v.z * v.z + (double)v.w * v.w;
        }
        nw_s[k] = (float)(a0 + a1);
    }
    if (tid < TT) {
        const float4* xr = (const float4*)(x + (size_t)(tb + tid) * DIM);
        double a0 = 0.0, a1 = 0.0;
        for (int q = 0; q < DIM / 4; ++q) {
            float4 v = xr[q];
            a0 += (double)v.x * v.x + (double)v.y * v.y;
            a1 += (double)v.z * v.z + (double)v.w * v.w;
        }
        nx_s[tid] = (float)(a0 + a1);
    }

    const int tr = tid >> 4;        // 0..15 token group (8 tokens each)
    const int tc = tid & 15;        // 0..15 code group  (8 codes each)
    const int st = tid >> 1;        // staging row 0..127
    const int sd = (tid & 1) << 4;  // staging d offset 0 / 16

    float best[8];
    int   bestk[8];
    #pragma unroll
    for (int i = 0; i < 8; ++i) { best[i] = 3.402823466e+38f; bestk[i] = 0; }

    for (int ct = 0; ct < NCODE / KTILE; ++ct) {
        float acc[8][8];
        #pragma unroll
        for (int i = 0; i < 8; ++i)
            #pragma unroll
            for (int j = 0; j < 8; ++j) acc[i][j] = 0.0f;

        for (int dt = 0; dt < DIM / DTILE; ++dt) {
            // global fetch before barrier (latency overlap)
            const float4* xsrc = (const float4*)(x + (size_t)(tb + st) * DIM + dt * DTILE + sd);
            const float4* wsrc = (const float4*)(W + (size_t)(ct * KTILE + st) * DIM + dt * DTILE + sd);
            float4 xv[4], wv[4];
            #pragma unroll
            for (int q = 0; q < 4; ++q) { xv[q] = xsrc[q]; wv[q] = wsrc[q]; }

            __syncthreads();   // protect previous tile's readers
            #pragma unroll
            for (int q = 0; q < 4; ++q) {
                const int dd = sd + (q << 2);
                xs[dd + 0][st] = xv[q].x; xs[dd + 1][st] = xv[q].y;
                xs[dd + 2][st] = xv[q].z; xs[dd + 3][st] = xv[q].w;
                ws[dd + 0][st] = wv[q].x; ws[dd + 1][st] = wv[q].y;
                ws[dd + 2][st] = wv[q].z; ws[dd + 3][st] = wv[q].w;
            }
            __syncthreads();

            #pragma unroll 8
            for (int d = 0; d < DTILE; ++d) {
                const float4* xa = (const float4*)&xs[d][tr << 3];
                const float4* wa = (const float4*)&ws[d][tc << 3];
                float4 a0 = xa[0], a1 = xa[1];
                float4 b0 = wa[0], b1 = wa[1];
                float xr8[8] = {a0.x, a0.y, a0.z, a0.w, a1.x, a1.y, a1.z, a1.w};
                float wr8[8] = {b0.x, b0.y, b0.z, b0.w, b1.x, b1.y, b1.z, b1.w};
                #pragma unroll
                for (int i = 0; i < 8; ++i)
                    #pragma unroll
                    for (int j = 0; j < 8; ++j)
                        acc[i][j] += xr8[i] * wr8[j];
            }
        }

        // epilogue: mirror ref: d = fl(fl(nx + nw) - 2*sim); k strictly
        // ascending across (ct, j) so strict '<' == first-occurrence argmin
        #pragma unroll
        for (int j = 0; j < 8; ++j) {
            const int k = ct * KTILE + (tc << 3) + j;
            const float nw = nw_s[k];
            #pragma unroll
            for (int i = 0; i < 8; ++i) {
                const float s  = nx_s[(tr << 3) + i] + nw;
                const float dv = s - 2.0f * acc[i][j];
                if (dv < best[i]) { best[i] = dv; bestk[i] = k; }
            }
        }
    }

    // ---- cross-thread argmin reduction (16 code-groups per token) ----
    __syncthreads();
    #pragma unroll
    for (int i = 0; i < 8; ++i) {
        red_d[tc][(tr << 3) + i] = best[i];
        red_k[tc][(tr << 3) + i] = bestk[i];
    }
    __syncthreads();
    if (tid < TT) {
        float bd = red_d[0][tid];
        int   bk = red_k[0][tid];
        #pragma unroll
        for (int c = 1; c < 16; ++c) {
            float d2 = red_d[c][tid];
            int   k2 = red_k[c][tid];
            if (d2 < bd || (d2 == bd && k2 < bk)) { bd = d2; bk = k2; }
        }
        bk_s[tid] = bk;
        outidx[tb + tid] = (float)bk;  // whole d_out read back as fp32
    }
    __syncthreads();

    // ---- gather codebook rows -> quantized output (coalesced float4) ----
    for (int i = tid; i < TT * (DIM / 4); i += 256) {
        const int t = i >> 6, j = i & 63;
        const float4* wr = (const float4*)(W + (size_t)bk_s[t] * DIM);
        ((float4*)(outq + (size_t)(tb + t) * DIM))[j] = wr[j];
    }
}

extern "C" void kernel_launch(void* const* d_in, const int* in_sizes, int n_in,
                              void* d_out, int out_size, void* d_ws, size_t ws_size,
                              hipStream_t stream) {
    const float* x = (const float*)d_in[0];
    const float* W = (const float*)d_in[1];
    float* outq   = (float*)d_out;
    float* outidx = outq + (size_t)NTOK * DIM;
    vq_kernel<<<NTOK / TT, 256, 0, stream>>>(x, W, outq, outidx);
}

// Round 2
// 556.757 us; speedup vs baseline: 1.0431x; 1.0431x over previous
//
#include <hip/hip_runtime.h>

#define NTOK   65536
#define DIM    256
#define NCODE  1024
#define TT     128   // tokens per block
#define KTILE  256   // code tile (4 passes over codes)
#define DTILE  32    // d tile

// 256 threads = 4 waves. Register tile: 8 tokens x 16 codes per thread.
// Wave-internal mapping 8 tr x 8 tc so every ds_read_b128 spans <=64 floats
// (2-way bank aliasing == free on gfx950, m136).
__global__ __launch_bounds__(256, 2) void vq_kernel(
    const float* __restrict__ x, const float* __restrict__ W,
    float* __restrict__ outq, float* __restrict__ outidx)
{
    __shared__ float xs[DTILE][TT];              // 16 KB, [d][token]
    __shared__ float ws_pool[DTILE * KTILE];     // 32 KB, [d][code]; aliased by reduction
    __shared__ float nw_s[NCODE];                // 4 KB
    __shared__ float nx_s[TT];                   // 512 B
    __shared__ int   bk_s[TT];                   // 512 B

    float (*ws)[KTILE] = (float (*)[KTILE])ws_pool;
    // reduction views alias ws_pool (GEMM done before reduction; barrier between)
    float (*red_d)[TT + 1] = (float (*)[TT + 1])ws_pool;                   // 16*129 floats
    int   (*red_k)[TT + 1] = (int   (*)[TT + 1])(ws_pool + 16 * (TT + 1)); // 16*129 ints

    const int tid = threadIdx.x;
    const int tb  = blockIdx.x * TT;

    // ---- phase 0: ||W_k||^2 (fp64 acc -> fp32) and ||x_t||^2 ----
    #pragma unroll
    for (int c = 0; c < 4; ++c) {
        const int k = (tid << 2) + c;
        const float4* wr = (const float4*)(W + (size_t)k * DIM);
        double a0 = 0.0, a1 = 0.0;
        for (int q = 0; q < DIM / 4; ++q) {
            float4 v = wr[q];
            a0 += (double)v.x * v.x + (double)v.y * v.y;
            a1 += (double)v.z * v.z + (double)v.w * v.w;
        }
        nw_s[k] = (float)(a0 + a1);
    }
    if (tid < TT) {
        const float4* xr = (const float4*)(x + (size_t)(tb + tid) * DIM);
        double a0 = 0.0, a1 = 0.0;
        for (int q = 0; q < DIM / 4; ++q) {
            float4 v = xr[q];
            a0 += (double)v.x * v.x + (double)v.y * v.y;
            a1 += (double)v.z * v.z + (double)v.w * v.w;
        }
        nx_s[tid] = (float)(a0 + a1);
    }

    // thread mapping: wave w, lane l; 8 tr x 8 tc inside a wave
    const int wv = tid >> 6, l = tid & 63;
    const int tr = ((wv >> 1) << 3) + (l >> 3);   // 0..15, token group (8 tokens)
    const int tc = ((wv & 1) << 3) + (l & 7);     // 0..15, code group (2x8 codes)
    const int st = tid >> 1;                      // x-staging row 0..127
    const int sd = (tid & 1) << 4;                // x-staging d offset 0/16

    float best[8];
    int   bestk[8];
    #pragma unroll
    for (int i = 0; i < 8; ++i) { best[i] = 3.402823466e+38f; bestk[i] = 0; }

    for (int ct = 0; ct < NCODE / KTILE; ++ct) {
        float acc[8][16];
        #pragma unroll
        for (int i = 0; i < 8; ++i)
            #pragma unroll
            for (int j = 0; j < 16; ++j) acc[i][j] = 0.0f;

        for (int dt = 0; dt < DIM / DTILE; ++dt) {
            // global fetch before barrier (overlaps other waves' compute)
            const float4* xsrc = (const float4*)(x + (size_t)(tb + st) * DIM + dt * DTILE + sd);
            const float4* wsrc = (const float4*)(W + (size_t)(ct * KTILE + tid) * DIM + dt * DTILE);
            float4 xv[4], wv4[8];
            #pragma unroll
            for (int q = 0; q < 4; ++q) xv[q] = xsrc[q];
            #pragma unroll
            for (int q = 0; q < 8; ++q) wv4[q] = wsrc[q];

            __syncthreads();   // protect previous tile's readers
            #pragma unroll
            for (int q = 0; q < 4; ++q) {
                const int dd = sd + (q << 2);
                xs[dd + 0][st] = xv[q].x; xs[dd + 1][st] = xv[q].y;
                xs[dd + 2][st] = xv[q].z; xs[dd + 3][st] = xv[q].w;
            }
            #pragma unroll
            for (int q = 0; q < 8; ++q) {
                const int dd = q << 2;
                ws[dd + 0][tid] = wv4[q].x; ws[dd + 1][tid] = wv4[q].y;
                ws[dd + 2][tid] = wv4[q].z; ws[dd + 3][tid] = wv4[q].w;
            }
            __syncthreads();

            #pragma unroll 8
            for (int d = 0; d < DTILE; ++d) {
                const float4* xa = (const float4*)&xs[d][tr << 3];
                const float4* wa = (const float4*)&ws[d][tc << 3];
                const float4* wb = (const float4*)&ws[d][128 + (tc << 3)];
                float4 a0 = xa[0], a1 = xa[1];
                float4 b0 = wa[0], b1 = wa[1];
                float4 c0 = wb[0], c1 = wb[1];
                float xr8[8]   = {a0.x, a0.y, a0.z, a0.w, a1.x, a1.y, a1.z, a1.w};
                float wr16[16] = {b0.x, b0.y, b0.z, b0.w, b1.x, b1.y, b1.z, b1.w,
                                  c0.x, c0.y, c0.z, c0.w, c1.x, c1.y, c1.z, c1.w};
                #pragma unroll
                for (int i = 0; i < 8; ++i)
                    #pragma unroll
                    for (int j = 0; j < 16; ++j)
                        acc[i][j] += xr8[i] * wr16[j];
            }
        }

        // epilogue: mirror ref fp32: d = fl(fl(nx+nw) - 2*sim); iterate j with
        // k strictly ascending (j<8: base+tc*8+j, j>=8: base+128+tc*8+j-8)
        #pragma unroll
        for (int j = 0; j < 16; ++j) {
            const int k = ct * KTILE + ((j < 8) ? ((tc << 3) + j) : (128 + (tc << 3) + j - 8));
            const float nw = nw_s[k];
            #pragma unroll
            for (int i = 0; i < 8; ++i) {
                const float s  = nx_s[(tr << 3) + i] + nw;
                const float dv = s - 2.0f * acc[i][j];
                if (dv < best[i]) { best[i] = dv; bestk[i] = k; }
            }
        }
    }

    // ---- cross-thread argmin reduction (16 code-groups per token) ----
    __syncthreads();   // last GEMM readers of ws_pool done; safe to alias
    #pragma unroll
    for (int i = 0; i < 8; ++i) {
        red_d[tc][(tr << 3) + i] = best[i];
        red_k[tc][(tr << 3) + i] = bestk[i];
    }
    __syncthreads();
    if (tid < TT) {
        float bd = red_d[0][tid];
        int   bk = red_k[0][tid];
        #pragma unroll
        for (int c = 1; c < 16; ++c) {
            float d2 = red_d[c][tid];
            int   k2 = red_k[c][tid];
            if (d2 < bd || (d2 == bd && k2 < bk)) { bd = d2; bk = k2; }
        }
        bk_s[tid] = bk;
        outidx[tb + tid] = (float)bk;  // d_out read back entirely as fp32
    }
    __syncthreads();

    // ---- gather codebook rows -> quantized output (coalesced float4) ----
    for (int i = tid; i < TT * (DIM / 4); i += 256) {
        const int t = i >> 6, j = i & 63;
        const float4* wr = (const float4*)(W + (size_t)bk_s[t] * DIM);
        ((float4*)(outq + (size_t)(tb + t) * DIM))[j] = wr[j];
    }
}

extern "C" void kernel_launch(void* const* d_in, const int* in_sizes, int n_in,
                              void* d_out, int out_size, void* d_ws, size_t ws_size,
                              hipStream_t stream) {
    const float* x = (const float*)d_in[0];
    const float* W = (const float*)d_in[1];
    float* outq   = (float*)d_out;
    float* outidx = outq + (size_t)NTOK * DIM;
    vq_kernel<<<NTOK / TT, 256, 0, stream>>>(x, W, outq, outidx);
}

// Round 4
// 319.890 us; speedup vs baseline: 1.8156x; 1.7405x over previous
//
#include <hip/hip_runtime.h>
#include <float.h>

typedef _Float16 half8  __attribute__((ext_vector_type(8)));
typedef _Float16 half4v __attribute__((ext_vector_type(4)));
typedef __fp16   fp16x2 __attribute__((ext_vector_type(2)));   // cvt_pkrtz return type
typedef float    f32x16 __attribute__((ext_vector_type(16)));

#define NTOK  65536
#define DIM   256
#define NCODE 1024
#define TT    128   // tokens per block

__device__ inline half8 pack8(float4 a, float4 b) {
    union { half8 v; fp16x2 h[4]; } u;
    u.h[0] = __builtin_amdgcn_cvt_pkrtz(a.x, a.y);
    u.h[1] = __builtin_amdgcn_cvt_pkrtz(a.z, a.w);
    u.h[2] = __builtin_amdgcn_cvt_pkrtz(b.x, b.y);
    u.h[3] = __builtin_amdgcn_cvt_pkrtz(b.z, b.w);
    return u.v;
}

// f16 MFMA coarse distances + top-4/half candidate tracking + exact fp32 rescore.
__global__ __launch_bounds__(256, 2) void vq_kernel(
    const float* __restrict__ x, const float* __restrict__ W,
    float* __restrict__ outq, float* __restrict__ outidx)
{
    // 64 KB W-tile (f16, xor-swizzled 16B chunks). First 32 KB aliased as
    // c_tile[128][128] (coarse scores, written after last MFMA read, barriers).
    __shared__ _Float16 wtile[128][256];
    __shared__ float nw_s[NCODE];
    __shared__ float nx_s[TT];
    __shared__ float mc_s[TT][2];
    __shared__ float bd_s[TT][2];
    __shared__ int   bk2_s[TT][2];
    __shared__ int   bk_s[TT];
    _Float16 (*c_tile)[128] = (_Float16 (*)[128])&wtile[0][0];

    const int tid = threadIdx.x;
    const int tb  = blockIdx.x * TT;
    const int wv  = tid >> 6, l = tid & 63;
    const int h   = l >> 5;            // k-half within MFMA fragment

    // ---- phase 0: ||W_k||^2 (fp64->fp32, mirrors ref accuracy), ||x_t||^2 ----
    #pragma unroll
    for (int c = 0; c < 4; ++c) {
        const int k = (tid << 2) + c;
        const float4* wr = (const float4*)(W + (size_t)k * DIM);
        double a0 = 0.0, a1 = 0.0;
        for (int q = 0; q < DIM / 4; ++q) {
            float4 v = wr[q];
            a0 += (double)v.x * v.x + (double)v.y * v.y;
            a1 += (double)v.z * v.z + (double)v.w * v.w;
        }
        nw_s[k] = (float)(a0 + a1);
    }
    if (tid < TT) {
        const float4* xr = (const float4*)(x + (size_t)(tb + tid) * DIM);
        double a0 = 0.0, a1 = 0.0;
        for (int q = 0; q < DIM / 4; ++q) {
            float4 v = xr[q];
            a0 += (double)v.x * v.x + (double)v.y * v.y;
            a1 += (double)v.z * v.z + (double)v.w * v.w;
        }
        nx_s[tid] = (float)(a0 + a1);
    }

    // ---- A-fragments (x in f16) held in registers, reused across all ct ----
    // A layout for 32x32x16: m = lane&31, k = 8*(lane>>5) + e
    const int trow = tb + (wv << 5) + (l & 31);
    half8 xa[16];
    #pragma unroll
    for (int s = 0; s < 16; ++s) {
        const float4* p = (const float4*)(x + (size_t)trow * DIM + (s << 4) + (h << 3));
        xa[s] = pack8(p[0], p[1]);
    }

    // per-thread top-4 candidates (thread = (token tid>>1, half tid&1))
    float c4[4] = {FLT_MAX, FLT_MAX, FLT_MAX, FLT_MAX};
    int   k4[4] = {0x7fffffff, 0x7fffffff, 0x7fffffff, 0x7fffffff};
    const int scan_t  = tid >> 1;
    const int scan_hh = tid & 1;

    for (int ct = 0; ct < 8; ++ct) {
        __syncthreads();   // prior readers of wtile/c_tile done
        // ---- stage W ct-tile: 128 codes x 256 k, f16, xor-swizzled ----
        {
            const int n  = tid >> 1, hh = tid & 1;
            const float4* src = (const float4*)(W + (size_t)(ct * 128 + n) * DIM + (hh << 7));
            #pragma unroll
            for (int i = 0; i < 16; ++i) {
                float4 a = src[2 * i], b = src[2 * i + 1];
                const int c  = (hh << 4) + i;           // 16B chunk index (k'>>3)
                const int p  = c ^ (n & 31);            // swizzled chunk
                *(half8*)&wtile[n][p << 3] = pack8(a, b);
            }
        }
        __syncthreads();

        // ---- MFMA: wave = 32 tokens x 128 codes, 16 k-steps x 4 n-tiles ----
        f32x16 acc[4];
        #pragma unroll
        for (int nt = 0; nt < 4; ++nt)
            #pragma unroll
            for (int e = 0; e < 16; ++e) acc[nt][e] = 0.0f;

        #pragma unroll
        for (int sp = 0; sp < 16; ++sp) {
            const int p = ((sp << 1) + h) ^ (l & 31);   // chunk swizzle (same for all nt)
            half8 b0 = *(const half8*)&wtile[(l & 31)      ][p << 3];
            half8 b1 = *(const half8*)&wtile[32 + (l & 31) ][p << 3];
            half8 b2 = *(const half8*)&wtile[64 + (l & 31) ][p << 3];
            half8 b3 = *(const half8*)&wtile[96 + (l & 31) ][p << 3];
            acc[0] = __builtin_amdgcn_mfma_f32_32x32x16_f16(xa[sp], b0, acc[0], 0, 0, 0);
            acc[1] = __builtin_amdgcn_mfma_f32_32x32x16_f16(xa[sp], b1, acc[1], 0, 0, 0);
            acc[2] = __builtin_amdgcn_mfma_f32_32x32x16_f16(xa[sp], b2, acc[2], 0, 0, 0);
            acc[3] = __builtin_amdgcn_mfma_f32_32x32x16_f16(xa[sp], b3, acc[3], 0, 0, 0);
        }

        // ---- epilogue: c = nw - 2*sim (coarse; per-token const nx dropped) ----
        __syncthreads();   // all MFMA reads of wtile done; alias as c_tile
        #pragma unroll
        for (int nt = 0; nt < 4; ++nt) {
            const int n = (nt << 5) + (l & 31);
            const float nw = nw_s[(ct << 7) + n];
            #pragma unroll
            for (int g = 0; g < 4; ++g) {
                half4v cv;
                #pragma unroll
                for (int r = 0; r < 4; ++r)
                    cv[r] = (_Float16)(nw - 2.0f * acc[nt][(g << 2) + r]);
                const int t0 = (wv << 5) + (g << 3) + (h << 2);  // C row = r + 8g + 4h
                *(half4v*)&c_tile[n][t0] = cv;
            }
        }
        __syncthreads();

        // ---- scan: update per-(token,half) top-4 over this tile ----
        for (int i = 0; i < 64; ++i) {
            const int n = (scan_hh << 6) + i;
            const float c = (float)c_tile[n][scan_t];
            if (c < c4[3]) {
                const int k = (ct << 7) + n;
                if (c < c4[2]) {
                    c4[3] = c4[2]; k4[3] = k4[2];
                    if (c < c4[1]) {
                        c4[2] = c4[1]; k4[2] = k4[1];
                        if (c < c4[0]) { c4[1] = c4[0]; k4[1] = k4[0]; c4[0] = c; k4[0] = k; }
                        else           { c4[1] = c;     k4[1] = k; }
                    } else { c4[2] = c; k4[2] = k; }
                } else { c4[3] = c; k4[3] = k; }
            }
        }
    }

    // ---- exchange coarse min between the token's two halves ----
    mc_s[scan_t][scan_hh] = c4[0];
    __syncthreads();
    const float mc  = fminf(mc_s[scan_t][0], mc_s[scan_t][1]);
    const float tau = 0.05f;   // >> coarse error (~1.3e-2); ~1.1 rescores/token

    // ---- exact fp32 rescore (mirrors ref: fl(fl(nx+nw) - 2*sim)) ----
    float bd = FLT_MAX; int bk = 0x7fffffff;
    {
        const float* xrow = x + (size_t)(tb + scan_t) * DIM;
        const float  nx   = nx_s[scan_t];
        #pragma unroll
        for (int j = 0; j < 4; ++j) {
            if (c4[j] <= mc + tau) {
                const int k = k4[j];
                const float* wrow = W + (size_t)k * DIM;
                float s0 = 0.f, s1 = 0.f, s2 = 0.f, s3 = 0.f;
                for (int d = 0; d < DIM; d += 4) {
                    float4 xv = *(const float4*)(xrow + d);
                    float4 wv = *(const float4*)(wrow + d);
                    s0 = fmaf(xv.x, wv.x, s0);
                    s1 = fmaf(xv.y, wv.y, s1);
                    s2 = fmaf(xv.z, wv.z, s2);
                    s3 = fmaf(xv.w, wv.w, s3);
                }
                const float sim = (s0 + s1) + (s2 + s3);
                const float dv  = (nx + nw_s[k]) - 2.0f * sim;
                if (dv < bd || (dv == bd && k < bk)) { bd = dv; bk = k; }
            }
        }
    }
    bd_s[scan_t][scan_hh] = bd; bk2_s[scan_t][scan_hh] = bk;
    __syncthreads();
    if (scan_hh == 0) {
        float d1 = bd_s[scan_t][1]; int k1 = bk2_s[scan_t][1];
        if (d1 < bd || (d1 == bd && k1 < bk)) { bk = k1; }
        bk_s[scan_t] = bk;
        outidx[tb + scan_t] = (float)bk;   // whole d_out read back as fp32
    }
    __syncthreads();

    // ---- gather codebook rows -> quantized output (coalesced float4) ----
    for (int i = tid; i < TT * (DIM / 4); i += 256) {
        const int t = i >> 6, j = i & 63;
        const float4* wr = (const float4*)(W + (size_t)bk_s[t] * DIM);
        ((float4*)(outq + (size_t)(tb + t) * DIM))[j] = wr[j];
    }
}

extern "C" void kernel_launch(void* const* d_in, const int* in_sizes, int n_in,
                              void* d_out, int out_size, void* d_ws, size_t ws_size,
                              hipStream_t stream) {
    const float* x = (const float*)d_in[0];
    const float* W = (const float*)d_in[1];
    float* outq   = (float*)d_out;
    float* outidx = outq + (size_t)NTOK * DIM;
    vq_kernel<<<NTOK / TT, 256, 0, stream>>>(x, W, outq, outidx);
}

// Round 6
// 195.798 us; speedup vs baseline: 2.9662x; 1.6338x over previous
//
#include <hip/hip_runtime.h>
#include <float.h>

typedef _Float16 half8  __attribute__((ext_vector_type(8)));
typedef __fp16   fp16x2 __attribute__((ext_vector_type(2)));
typedef float    f32x16 __attribute__((ext_vector_type(16)));

#define NTOK  65536
#define DIM   256
#define NCODE 1024
#define TT    128
#define CAP   4096
#define TAU   0.08f
#define BIAS  64.0f   // makes coarse scores strictly positive: c >= 64+nw-2|sim| > 17

__device__ inline half8 pack8(float4 a, float4 b) {
    union { half8 v; fp16x2 h[4]; } u;
    u.h[0] = __builtin_amdgcn_cvt_pkrtz(a.x, a.y);
    u.h[1] = __builtin_amdgcn_cvt_pkrtz(a.z, a.w);
    u.h[2] = __builtin_amdgcn_cvt_pkrtz(b.x, b.y);
    u.h[3] = __builtin_amdgcn_cvt_pkrtz(b.z, b.w);
    return u.v;
}
__device__ inline unsigned umn(unsigned a, unsigned b) { return a < b ? a : b; }
__device__ inline unsigned umx(unsigned a, unsigned b) { return a > b ? a : b; }

// pre-kernel: ||W_k||^2 (fp64->fp32) + W -> f16 chunks (row-major half8)
__global__ __launch_bounds__(256) void prep_kernel(const float* __restrict__ W,
                                                   float* __restrict__ nw_out,
                                                   half8* __restrict__ wh_out) {
    const int k = blockIdx.x * 256 + threadIdx.x;   // grid = 4
    const float4* wr = (const float4*)(W + (size_t)k * DIM);
    half8* dst = wh_out + (size_t)k * (DIM / 8);
    double a0 = 0.0, a1 = 0.0;
    for (int q = 0; q < DIM / 8; ++q) {
        float4 u = wr[2 * q], v = wr[2 * q + 1];
        a0 += (double)u.x * u.x + (double)u.y * u.y + (double)v.x * v.x + (double)v.y * v.y;
        a1 += (double)u.z * u.z + (double)u.w * u.w + (double)v.z * v.z + (double)v.w * v.w;
        dst[q] = pack8(u, v);
    }
    nw_out[k] = (float)(a0 + a1);
}

template <bool PRE>
__global__ __launch_bounds__(256, 2) void vq_kernel(
    const float* __restrict__ x, const float* __restrict__ W,
    const float* __restrict__ nwp, const half8* __restrict__ whp,
    float* __restrict__ outq, float* __restrict__ outidx)
{
    __shared__ _Float16 wtile[128][256];            // 64 KB; aliased as cand list after loop
    __shared__ float nw_s[NCODE];
    __shared__ float nx_s[TT];
    __shared__ double nxd[TT][2];
    __shared__ unsigned long long best64[TT];
    __shared__ int cnt_s;
    __shared__ int bk_s[TT];
    unsigned* cand = (unsigned*)&wtile[0][0];

    const int tid = threadIdx.x, tb = blockIdx.x * TT;
    const int wv = tid >> 6, l = tid & 63, h = l >> 5, ln = l & 31;

    // ---- nw: load precomputed, or fp64 in-block fallback ----
    if (PRE) {
        ((float4*)nw_s)[tid] = ((const float4*)nwp)[tid];
    } else {
        #pragma unroll
        for (int c = 0; c < 4; ++c) {
            const int k = (tid << 2) + c;
            const float4* wr = (const float4*)(W + (size_t)k * DIM);
            double a0 = 0.0, a1 = 0.0;
            for (int q = 0; q < DIM / 4; ++q) {
                float4 v = wr[q];
                a0 += (double)v.x * v.x + (double)v.y * v.y;
                a1 += (double)v.z * v.z + (double)v.w * v.w;
            }
            nw_s[k] = (float)(a0 + a1);
        }
    }
    // ---- nx (fp64, two half-row partials per token) ----
    {
        const int t = tid >> 1, hh = tid & 1;
        const float4* xr = (const float4*)(x + (size_t)(tb + t) * DIM + hh * 128);
        double a0 = 0.0, a1 = 0.0;
        for (int q = 0; q < 32; ++q) {
            float4 v = xr[q];
            a0 += (double)v.x * v.x + (double)v.y * v.y;
            a1 += (double)v.z * v.z + (double)v.w * v.w;
        }
        nxd[t][hh] = a0 + a1;
    }
    if (tid == 0) cnt_s = 0;
    __syncthreads();
    if (tid < TT) { nx_s[tid] = (float)(nxd[tid][0] + nxd[tid][1]); best64[tid] = ~0ull; }

    // ---- A-fragments in registers (reused across all ct) ----
    const int trow = tb + (wv << 5) + ln;
    half8 xa[16];
    #pragma unroll
    for (int s = 0; s < 16; ++s) {
        const float4* p = (const float4*)(x + (size_t)trow * DIM + (s << 4) + (h << 3));
        xa[s] = pack8(p[0], p[1]);
    }

    // per-lane top-2 packed keys per C-reg row slot (16 token rows)
    unsigned b0[16], b1[16];
    #pragma unroll
    for (int e = 0; e < 16; ++e) { b0[e] = 0xFFFFFFFFu; b1[e] = 0xFFFFFFFFu; }

    for (int ct = 0; ct < 8; ++ct) {
        __syncthreads();   // prior MFMA readers of wtile done
        if (PRE) {
            // coalesced f16 chunk staging: thread handles chunks j*256+tid
            half8 v[16];
            #pragma unroll
            for (int j = 0; j < 16; ++j)
                v[j] = whp[(size_t)ct * 4096 + j * 256 + tid];
            #pragma unroll
            for (int j = 0; j < 16; ++j) {
                const int g = j * 256 + tid;
                const int n = g >> 5, c = g & 31, p = c ^ (n & 31);
                *(half8*)&wtile[n][p << 3] = v[j];
            }
        } else {
            const int n = tid >> 1, hh = tid & 1;
            const float4* src = (const float4*)(W + (size_t)(ct * 128 + n) * DIM + (hh << 7));
            #pragma unroll
            for (int i = 0; i < 16; ++i) {
                float4 a = src[2 * i], b = src[2 * i + 1];
                const int c = (hh << 4) + i, p = c ^ (n & 31);
                *(half8*)&wtile[n][p << 3] = pack8(a, b);
            }
        }
        __syncthreads();

        f32x16 acc[4];
        #pragma unroll
        for (int nt = 0; nt < 4; ++nt)
            #pragma unroll
            for (int e = 0; e < 16; ++e) acc[nt][e] = 0.0f;

        #pragma unroll
        for (int sp = 0; sp < 16; ++sp) {
            const int p = ((sp << 1) + h) ^ ln;
            half8 q0 = *(const half8*)&wtile[ln     ][p << 3];
            half8 q1 = *(const half8*)&wtile[32 + ln][p << 3];
            half8 q2 = *(const half8*)&wtile[64 + ln][p << 3];
            half8 q3 = *(const half8*)&wtile[96 + ln][p << 3];
            acc[0] = __builtin_amdgcn_mfma_f32_32x32x16_f16(xa[sp], q0, acc[0], 0, 0, 0);
            acc[1] = __builtin_amdgcn_mfma_f32_32x32x16_f16(xa[sp], q1, acc[1], 0, 0, 0);
            acc[2] = __builtin_amdgcn_mfma_f32_32x32x16_f16(xa[sp], q2, acc[2], 0, 0, 0);
            acc[3] = __builtin_amdgcn_mfma_f32_32x32x16_f16(xa[sp], q3, acc[3], 0, 0, 0);
        }

        // ---- branch-free register top-2 on packed (score,k) keys ----
        // score biased by +64 so it is ALWAYS POSITIVE -> uint order == float
        // order (R5 bug: unbiased scores go negative, uint compare reverses)
        #pragma unroll
        for (int nt = 0; nt < 4; ++nt) {
            const int kk = (ct << 7) + (nt << 5) + ln;
            const float nwb = nw_s[kk] + BIAS;
            #pragma unroll
            for (int e = 0; e < 16; ++e) {
                const float c = fmaf(acc[nt][e], -2.0f, nwb);
                const unsigned u = (__float_as_uint(c) & 0xFFFFFC00u) | (unsigned)kk;
                const unsigned lo = umn(u, b0[e]), hi = umx(u, b0[e]);
                b0[e] = lo;
                b1[e] = umn(hi, b1[e]);
            }
        }
    }

    __syncthreads();   // all MFMA reads of wtile done; alias as cand list

    // ---- per-row: cross-lane coarse min (32 lanes, same h), tau-trigger, append ----
    #pragma unroll
    for (int e = 0; e < 16; ++e) {
        unsigned v = b0[e];
        #pragma unroll
        for (int m = 1; m <= 16; m <<= 1) v = umn(v, (unsigned)__shfl_xor((int)v, m));
        const float thr = __uint_as_float(v & 0xFFFFFC00u) + TAU;
        const int t = (wv << 5) + (e & 3) + ((e >> 2) << 3) + (h << 2);
        if (__uint_as_float(b0[e] & 0xFFFFFC00u) <= thr) {
            int i = atomicAdd(&cnt_s, 1);
            if (i < CAP) cand[i] = ((unsigned)t << 10) | (b0[e] & 1023u);
        }
        if (__uint_as_float(b1[e] & 0xFFFFFC00u) <= thr) {
            int i = atomicAdd(&cnt_s, 1);
            if (i < CAP) cand[i] = ((unsigned)t << 10) | (b1[e] & 1023u);
        }
    }
    __syncthreads();

    // ---- wave-cooperative exact fp32 rescore; lexicographic (dv,k) atomicMin ----
    const int nc = min(cnt_s, CAP);
    for (int c = wv; c < nc; c += 4) {
        const unsigned en = cand[c];
        const int t = en >> 10, k = en & 1023;
        float4 xv = ((const float4*)(x + (size_t)(tb + t) * DIM))[l];
        float4 wr = ((const float4*)(W + (size_t)k * DIM))[l];
        float s = fmaf(xv.x, wr.x, fmaf(xv.y, wr.y, fmaf(xv.z, wr.z, xv.w * wr.w)));
        #pragma unroll
        for (int m = 1; m <= 32; m <<= 1) s += __shfl_xor(s, m);
        const float dv = (nx_s[t] + nw_s[k]) - 2.0f * s;
        if (l == 0) {
            unsigned long long key = ((unsigned long long)__float_as_uint(dv) << 32) | (unsigned)k;
            atomicMin(&best64[t], key);
        }
    }
    __syncthreads();

    if (tid < TT) {
        const int bk = (int)(best64[tid] & 1023u);
        bk_s[tid] = bk;
        outidx[tb + tid] = (float)bk;   // whole d_out read back as fp32
    }
    __syncthreads();

    // ---- gather codebook rows -> quantized output (coalesced float4) ----
    for (int i = tid; i < TT * (DIM / 4); i += 256) {
        const int t = i >> 6, j = i & 63;
        const float4* wr = (const float4*)(W + (size_t)bk_s[t] * DIM);
        ((float4*)(outq + (size_t)(tb + t) * DIM))[j] = wr[j];
    }
}

extern "C" void kernel_launch(void* const* d_in, const int* in_sizes, int n_in,
                              void* d_out, int out_size, void* d_ws, size_t ws_size,
                              hipStream_t stream) {
    const float* x = (const float*)d_in[0];
    const float* W = (const float*)d_in[1];
    float* outq   = (float*)d_out;
    float* outidx = outq + (size_t)NTOK * DIM;

    const size_t need = 4096 + (size_t)NCODE * DIM * sizeof(_Float16);
    if (ws_size >= need) {
        float* nw_ws = (float*)d_ws;
        half8* wh_ws = (half8*)((char*)d_ws + 4096);
        prep_kernel<<<NCODE / 256, 256, 0, stream>>>(W, nw_ws, wh_ws);
        vq_kernel<true><<<NTOK / TT, 256, 0, stream>>>(x, W, nw_ws, wh_ws, outq, outidx);
    } else {
        vq_kernel<false><<<NTOK / TT, 256, 0, stream>>>(x, W, nullptr, nullptr, outq, outidx);
    }
}